// Round 9
// baseline (88.089 us; speedup 1.0000x reference)
//
#include <hip/hip_runtime.h>
#include <math.h>

#define N 512
#define MAX_ITERS 1024
#define NWORK 8                // worker blocks, elected onto ONE XCD
#define NLAUNCH 64             // pigeonhole: some XCD hosts >= 8 of 64 blocks
#define TPB 512                // == N: every thread owns one column
#define NWAVES 8
#define RPW 8                  // rows per wave (NWORK*NWAVES*RPW == N)
#define REL_TOL 1e-5f
#define POISON 0xAAAAAAAAu
#define TOKEN 0x5A5A5A5Au

// ws (unsigned[], poison 0xAAAAAAAA every launch):
//   [0..15] cnt[xcd] tickets, [16] winner CAS, [17..24] doneflag[slot]
// Slice exchange: float Part[2][NWORK][N] = 32 KB in d_out rows 0..15; clobbered
// by slot 0's epilogue only after all doneflags post. Sync is carried by DATA:
// iter i publishes with sign (-1)^((i>>1)&1) (alternates per buffer reuse);
// readers spin until the expected sign appears on all 8 slices. Poison is
// negative; first expected sign of both buffers is +.
// Proven: agent scope (sc1) is the visibility point (sc0/SE hangs — R6);
// 8 sc1 loads batched behind ONE s_waitcnt = one RT per poll round (R7).

__device__ __forceinline__ void wg_store_f(float* p, float v) {
    __hip_atomic_store(p, v, __ATOMIC_RELAXED, __HIP_MEMORY_SCOPE_WORKGROUP);
}

__device__ __forceinline__ unsigned read_xcc_id() {
    return __builtin_amdgcn_s_getreg(20 | (3 << 11)) & 15u;   // HW_REG_XCC_ID
}

// 8 agent-scope (sc1) loads in flight, one waitcnt: ~one round trip.
__device__ __forceinline__ void load8_sc1(const float* b0, const float* b1,
                                          const float* b2, const float* b3,
                                          const float* b4, const float* b5,
                                          const float* b6, const float* b7,
                                          float& x0, float& x1, float& x2, float& x3,
                                          float& x4, float& x5, float& x6, float& x7) {
    asm volatile(
        "global_load_dword %0, %[a0], off sc1\n\t"
        "global_load_dword %1, %[a1], off sc1\n\t"
        "global_load_dword %2, %[a2], off sc1\n\t"
        "global_load_dword %3, %[a3], off sc1\n\t"
        "global_load_dword %4, %[a4], off sc1\n\t"
        "global_load_dword %5, %[a5], off sc1\n\t"
        "global_load_dword %6, %[a6], off sc1\n\t"
        "global_load_dword %7, %[a7], off sc1\n\t"
        "s_waitcnt vmcnt(0)"
        : "=&v"(x0), "=&v"(x1), "=&v"(x2), "=&v"(x3),
          "=&v"(x4), "=&v"(x5), "=&v"(x6), "=&v"(x7)
        : [a0]"v"(b0), [a1]"v"(b1), [a2]"v"(b2), [a3]"v"(b3),
          [a4]"v"(b4), [a5]"v"(b5), [a6]"v"(b6), [a7]"v"(b7)
        : "memory");
}

// Spin-gather all NWORK slices of `tag`, fixed-order sum -> C value for col tid.
__device__ __forceinline__ float gather_c(const float* Part, int tag, int tid) {
    const float* base = Part + (tag & 1) * (NWORK * N) + tid;
    const float sgn = ((tag >> 1) & 1) ? -1.0f : 1.0f;
    float v0, v1, v2, v3, v4, v5, v6, v7;
    bool ok;
    do {
        load8_sc1(base, base + N, base + 2 * N, base + 3 * N,
                  base + 4 * N, base + 5 * N, base + 6 * N, base + 7 * N,
                  v0, v1, v2, v3, v4, v5, v6, v7);
        ok = (v0 * sgn > 0.0f) & (v1 * sgn > 0.0f) &
             (v2 * sgn > 0.0f) & (v3 * sgn > 0.0f) &
             (v4 * sgn > 0.0f) & (v5 * sgn > 0.0f) &
             (v6 * sgn > 0.0f) & (v7 * sgn > 0.0f);
    } while (!ok);
    float s = ((v0 + v1) + (v2 + v3)) + ((v4 + v5) + (v6 + v7));
    return sgn / s;
}

__global__ __launch_bounds__(TPB, 2)
void sinkhorn_persistent(const float* __restrict__ W, float* out, unsigned* ws) {
    unsigned* cnt      = ws;        // [16]
    unsigned* winner   = ws + 16;
    unsigned* doneflag = ws + 17;   // [NWORK]
    float* Part = out;              // [2][NWORK][N]

    __shared__ __align__(16) float vec[N];
    __shared__ __align__(16) float wpart[NWAVES][N];
    __shared__ unsigned swflag[NWAVES];
    __shared__ unsigned sflag;
    __shared__ unsigned s_ticket, s_xcd, s_win;

    const int tid  = threadIdx.x;   // == owned column (TPB == N)
    const int wave = tid >> 6;
    const int lane = tid & 63;

    // ---------------- election, phase 1: draw a ticket ----------------
    if (tid == 0) {
        unsigned xcd = read_xcc_id();
        unsigned ticket = __hip_atomic_fetch_add(&cnt[xcd], 1u, __ATOMIC_RELAXED,
                                                 __HIP_MEMORY_SCOPE_AGENT) - POISON;
        s_ticket = ticket; s_xcd = xcd;
        if (ticket == NWORK - 1) {
            unsigned expected = POISON;
            __hip_atomic_compare_exchange_strong(winner, &expected, xcd,
                                                 __ATOMIC_RELAXED, __ATOMIC_RELAXED,
                                                 __HIP_MEMORY_SCOPE_AGENT);
        }
    }
    __syncthreads();
    const unsigned slot = s_ticket;
    if (slot >= NWORK) return;      // can't be a worker on any XCD

    // ---------------- tentative matrix load (overlaps winner wait) ----------
    // float4 layout: row fragment = cols {4*lane..+3} and {4*lane+256..+259}.
    const int r0 = ((int)slot * NWAVES + wave) * RPW;
    const float4* W4 = (const float4*)W;   // row pitch 128 float4
    float4 wr[RPW][2];
#pragma unroll
    for (int a = 0; a < RPW; ++a)
#pragma unroll
        for (int kk = 0; kk < 2; ++kk) {
            float4 t = W4[(r0 + a) * 128 + lane + 64 * kk];
            wr[a][kk] = make_float4(fabsf(t.x), fabsf(t.y), fabsf(t.z), fabsf(t.w));
        }

    // ---------------- election, phase 2: resolve winner ----------------
    if (tid == 0) {
        unsigned w;
        while ((w = __hip_atomic_load(winner, __ATOMIC_RELAXED,
                                      __HIP_MEMORY_SCOPE_AGENT)) == POISON) {}
        s_win = (s_xcd == w) ? 1u : 0u;
    }
    __syncthreads();
    if (!s_win) return;

    float4* const vec4 = (float4*)vec;
    float4* const wp4  = (float4*)&wpart[wave][0];

    // Identical committed slice values + FIXED summation trees -> bitwise-
    // identical trajectories in all workers -> uniform convergence break.
    float c = 1.0f, h1 = 1.0f, h2 = 1.0f, cchk = 1.0f;
    float Rv[RPW];
#pragma unroll
    for (int a = 0; a < RPW; ++a) Rv[a] = 0.0f;
    int last = MAX_ITERS - 1;

    for (int iter = 0; iter < MAX_ITERS; ++iter) {
        bool chk = false;
        unsigned anyv = 0;
        if (iter > 0) {
            c = gather_c(Part, iter - 1, tid);
            chk = ((iter & 1) == 0) && (iter >= 10);
            if (chk) {
                bool nc = fabsf(c - cchk) > REL_TOL * fabsf(c);
                cchk = c;
                anyv = (unsigned)__any(nc);
            }
            // safeguarded componentwise Aitken delta^2 every 4 iters
            if ((iter & 3) == 0 && iter >= 8) {
                float d1 = c - h1, d0 = h1 - h2;
                float dd = d1 - d0;
                if (fabsf(dd) > 1e-9f * fabsf(c)) {
                    float cx = c - d1 * d1 / dd;
                    if (cx > 0.25f * c && cx < 4.0f * c) c = cx;
                }
            }
            h2 = h1; h1 = c;
        }

        vec[tid] = c;
        if (chk && lane == 0) swflag[wave] = anyv;
        __syncthreads();

        // ---- row step: R_r = 1 / sum_j |W0|[r][j] * C_j (fixed tree) ----
        float4 va = vec4[lane], vb = vec4[lane + 64];
        float s[RPW];
#pragma unroll
        for (int a = 0; a < RPW; ++a)
            s[a] = ((wr[a][0].x * va.x + wr[a][0].y * va.y) +
                    (wr[a][0].z * va.z + wr[a][0].w * va.w)) +
                   ((wr[a][1].x * vb.x + wr[a][1].y * vb.y) +
                    (wr[a][1].z * vb.z + wr[a][1].w * vb.w));
#pragma unroll
        for (int off = 32; off > 0; off >>= 1)
#pragma unroll
            for (int a = 0; a < RPW; ++a) s[a] += __shfl_xor(s[a], off, 64);
#pragma unroll
        for (int a = 0; a < RPW; ++a) Rv[a] = 1.0f / s[a];

        // convergence vote rides the existing syncs (off the critical path)
        if (chk && tid == 0) {
            unsigned f = 0;
#pragma unroll
            for (int w = 0; w < NWAVES; ++w) f |= swflag[w];
            sflag = f;
        }

        // ---- column partials + signed publish ----
        float4 p0 = make_float4(0.f, 0.f, 0.f, 0.f), p1 = p0;
#pragma unroll
        for (int a = 0; a < RPW; ++a) {
            p0.x += wr[a][0].x * Rv[a]; p0.y += wr[a][0].y * Rv[a];
            p0.z += wr[a][0].z * Rv[a]; p0.w += wr[a][0].w * Rv[a];
            p1.x += wr[a][1].x * Rv[a]; p1.y += wr[a][1].y * Rv[a];
            p1.z += wr[a][1].z * Rv[a]; p1.w += wr[a][1].w * Rv[a];
        }
        wp4[lane] = p0;
        wp4[lane + 64] = p1;
        __syncthreads();
        {
            float P = 0.0f;
#pragma unroll
            for (int w = 0; w < NWAVES; ++w) P += wpart[w][tid];   // fixed order
            const float sgnp = ((iter >> 1) & 1) ? -1.0f : 1.0f;
            wg_store_f(&Part[(iter & 1) * (NWORK * N) + slot * N + tid], sgnp * P);
        }
        // Break AFTER publish (uniform across workers); epilogue re-pairs via a
        // final gather so the result ends on a column-normalize like the ref.
        if (chk && sflag == 0) { last = iter; break; }
    }

    // ---- final gather: c = colstep(Rv_last) -> columns sum exactly to 1 ----
    c = gather_c(Part, last, tid);
    __syncthreads();   // all this block's gather loads done before doneflag
    if (tid == 0)
        __hip_atomic_store(&doneflag[slot], TOKEN, __ATOMIC_RELEASE,
                           __HIP_MEMORY_SCOPE_AGENT);
    if (slot == 0) {   // slot 0's rows overlap the Part region — wait for all
        if (tid < NWORK)
            while (__hip_atomic_load(&doneflag[tid], __ATOMIC_ACQUIRE,
                                     __HIP_MEMORY_SCOPE_AGENT) != TOKEN) {}
        __syncthreads();
    }

    // ---- epilogue: out[i][j] = |W0[i][j]| * R_i * C_j (float4 stores) ----
    vec[tid] = c;
    __syncthreads();
    float4 va = vec4[lane], vb = vec4[lane + 64];
    float4* out4 = (float4*)out;
#pragma unroll
    for (int a = 0; a < RPW; ++a) {
        float4 o0, o1;
        o0.x = wr[a][0].x * Rv[a] * va.x; o0.y = wr[a][0].y * Rv[a] * va.y;
        o0.z = wr[a][0].z * Rv[a] * va.z; o0.w = wr[a][0].w * Rv[a] * va.w;
        o1.x = wr[a][1].x * Rv[a] * vb.x; o1.y = wr[a][1].y * Rv[a] * vb.y;
        o1.z = wr[a][1].z * Rv[a] * vb.z; o1.w = wr[a][1].w * Rv[a] * vb.w;
        out4[(r0 + a) * 128 + lane] = o0;
        out4[(r0 + a) * 128 + lane + 64] = o1;
    }
}

extern "C" void kernel_launch(void* const* d_in, const int* in_sizes, int n_in,
                              void* d_out, int out_size, void* d_ws, size_t ws_size,
                              hipStream_t stream) {
    const float* weight = (const float*)d_in[0];
    float* out = (float*)d_out;
    unsigned* ws = (unsigned*)d_ws;

    sinkhorn_persistent<<<NLAUNCH, TPB, 0, stream>>>(weight, out, ws);
}

// Round 10
// 82.407 us; speedup vs baseline: 1.0690x; 1.0690x over previous
//
#include <hip/hip_runtime.h>
#include <math.h>

#define N 512
#define MAX_ITERS 1024
#define NWORK 8                // worker blocks, elected onto ONE XCD
#define NLAUNCH 64             // pigeonhole: some XCD hosts >= 8 of 64 blocks
#define TPB 512                // == N: every thread owns one column
#define NWAVES 8
#define RPW 8                  // rows per wave (NWORK*NWAVES*RPW == N)
#define REL_TOL 1e-5f
#define POISON 0xAAAAAAAAu
#define TOKEN 0x5A5A5A5Au

// ws (unsigned[], poison 0xAAAAAAAA every launch):
//   [0..15] cnt[xcd] tickets, [16] winner CAS, [17..24] doneflag[slot]
// Slice exchange: float Part[2][NWORK][N] = 32 KB in d_out rows 0..15; clobbered
// by slot 0's epilogue only after all doneflags post. Sync is carried by DATA:
// iter i publishes with sign (-1)^((i>>1)&1) (alternates per buffer reuse);
// readers spin until the expected sign appears on all 8 slices. Poison is
// negative; first expected sign of both buffers is +.
// Proven: agent scope (sc1) is the visibility point (sc0/SE hangs — R6);
// 8 sc1 loads batched behind ONE s_waitcnt = one RT per poll round (R7).
// R10: publish also at agent scope (eager push toward IC, not lazy writeback).

__device__ __forceinline__ void agent_store_f(float* p, float v) {
    __hip_atomic_store(p, v, __ATOMIC_RELAXED, __HIP_MEMORY_SCOPE_AGENT);
}

__device__ __forceinline__ unsigned read_xcc_id() {
    return __builtin_amdgcn_s_getreg(20 | (3 << 11)) & 15u;   // HW_REG_XCC_ID
}

// 8 agent-scope (sc1) loads in flight, one waitcnt: ~one round trip.
__device__ __forceinline__ void load8_sc1(const float* b0, const float* b1,
                                          const float* b2, const float* b3,
                                          const float* b4, const float* b5,
                                          const float* b6, const float* b7,
                                          float& x0, float& x1, float& x2, float& x3,
                                          float& x4, float& x5, float& x6, float& x7) {
    asm volatile(
        "global_load_dword %0, %[a0], off sc1\n\t"
        "global_load_dword %1, %[a1], off sc1\n\t"
        "global_load_dword %2, %[a2], off sc1\n\t"
        "global_load_dword %3, %[a3], off sc1\n\t"
        "global_load_dword %4, %[a4], off sc1\n\t"
        "global_load_dword %5, %[a5], off sc1\n\t"
        "global_load_dword %6, %[a6], off sc1\n\t"
        "global_load_dword %7, %[a7], off sc1\n\t"
        "s_waitcnt vmcnt(0)"
        : "=&v"(x0), "=&v"(x1), "=&v"(x2), "=&v"(x3),
          "=&v"(x4), "=&v"(x5), "=&v"(x6), "=&v"(x7)
        : [a0]"v"(b0), [a1]"v"(b1), [a2]"v"(b2), [a3]"v"(b3),
          [a4]"v"(b4), [a5]"v"(b5), [a6]"v"(b6), [a7]"v"(b7)
        : "memory");
}

// Spin-gather all NWORK slices of `tag`, fixed-order sum -> C value for col tid.
__device__ __forceinline__ float gather_c(const float* Part, int tag, int tid) {
    const float* base = Part + (tag & 1) * (NWORK * N) + tid;
    const float sgn = ((tag >> 1) & 1) ? -1.0f : 1.0f;
    float v0, v1, v2, v3, v4, v5, v6, v7;
    bool ok;
    do {
        load8_sc1(base, base + N, base + 2 * N, base + 3 * N,
                  base + 4 * N, base + 5 * N, base + 6 * N, base + 7 * N,
                  v0, v1, v2, v3, v4, v5, v6, v7);
        ok = (v0 * sgn > 0.0f) & (v1 * sgn > 0.0f) &
             (v2 * sgn > 0.0f) & (v3 * sgn > 0.0f) &
             (v4 * sgn > 0.0f) & (v5 * sgn > 0.0f) &
             (v6 * sgn > 0.0f) & (v7 * sgn > 0.0f);
    } while (!ok);
    float s = ((v0 + v1) + (v2 + v3)) + ((v4 + v5) + (v6 + v7));
    return sgn / s;
}

__global__ __launch_bounds__(TPB, 2)
void sinkhorn_persistent(const float* __restrict__ W, float* out, unsigned* ws) {
    unsigned* cnt      = ws;        // [16]
    unsigned* winner   = ws + 16;
    unsigned* doneflag = ws + 17;   // [NWORK]
    float* Part = out;              // [2][NWORK][N]

    __shared__ __align__(16) float vec[N];
    __shared__ __align__(16) float wpart[NWAVES][N];
    __shared__ unsigned swflag[NWAVES];
    __shared__ unsigned sflag;
    __shared__ unsigned s_ticket, s_xcd, s_win;

    const int tid  = threadIdx.x;   // == owned column (TPB == N)
    const int wave = tid >> 6;
    const int lane = tid & 63;

    // ---------------- election, phase 1: draw a ticket ----------------
    if (tid == 0) {
        unsigned xcd = read_xcc_id();
        unsigned ticket = __hip_atomic_fetch_add(&cnt[xcd], 1u, __ATOMIC_RELAXED,
                                                 __HIP_MEMORY_SCOPE_AGENT) - POISON;
        s_ticket = ticket; s_xcd = xcd;
        if (ticket == NWORK - 1) {
            unsigned expected = POISON;
            __hip_atomic_compare_exchange_strong(winner, &expected, xcd,
                                                 __ATOMIC_RELAXED, __ATOMIC_RELAXED,
                                                 __HIP_MEMORY_SCOPE_AGENT);
        }
    }
    __syncthreads();
    const unsigned slot = s_ticket;
    if (slot >= NWORK) return;      // can't be a worker on any XCD

    // ---------------- tentative matrix load (overlaps winner wait) ----------
    const int r0 = ((int)slot * NWAVES + wave) * RPW;
    const float4* W4 = (const float4*)W;   // row pitch 128 float4
    float4 wr[RPW][2];
#pragma unroll
    for (int a = 0; a < RPW; ++a)
#pragma unroll
        for (int kk = 0; kk < 2; ++kk) {
            float4 t = W4[(r0 + a) * 128 + lane + 64 * kk];
            wr[a][kk] = make_float4(fabsf(t.x), fabsf(t.y), fabsf(t.z), fabsf(t.w));
        }

    // ---------------- election, phase 2: resolve winner ----------------
    if (tid == 0) {
        unsigned w;
        while ((w = __hip_atomic_load(winner, __ATOMIC_RELAXED,
                                      __HIP_MEMORY_SCOPE_AGENT)) == POISON) {}
        s_win = (s_xcd == w) ? 1u : 0u;
    }
    __syncthreads();
    if (!s_win) return;

    float4* const vec4 = (float4*)vec;
    float4* const wp4  = (float4*)&wpart[wave][0];

    // Identical committed slice values + FIXED summation trees -> bitwise-
    // identical trajectories in all workers -> uniform convergence break.
    float c = 1.0f, h1 = 1.0f, h2 = 1.0f, cchk = 1.0f;
    float Rv[RPW];
#pragma unroll
    for (int a = 0; a < RPW; ++a) Rv[a] = 0.0f;
    int last = MAX_ITERS - 1;
    int extrap_cd = 9;   // next extrap when countdown hits 0 (iter 9, then every 3)

    for (int iter = 0; iter < MAX_ITERS; ++iter) {
        bool chk = false;
        unsigned anyv = 0;
        if (iter > 0) {
            c = gather_c(Part, iter - 1, tid);
            chk = (iter >= 8);
            if (chk) {
                bool nc = fabsf(c - cchk) > REL_TOL * fabsf(c);
                cchk = c;
                anyv = (unsigned)__any(nc);
            }
            // safeguarded componentwise Aitken delta^2 every 3 iters (start 9):
            // points e+1..e+3 after an extrap at e are a clean plain orbit ->
            // both diffs are geometric -> cadence 3 is the fastest valid schedule.
            if (--extrap_cd == 0) {
                extrap_cd = 3;
                float d1 = c - h1, d0 = h1 - h2;
                float dd = d1 - d0;
                if (fabsf(dd) > 1e-9f * fabsf(c)) {
                    float cx = c - d1 * d1 / dd;
                    if (cx > 0.25f * c && cx < 4.0f * c) c = cx;
                }
            }
            h2 = h1; h1 = c;
        }

        vec[tid] = c;
        if (chk && lane == 0) swflag[wave] = anyv;
        __syncthreads();

        // ---- row step: R_r = 1 / sum_j |W0|[r][j] * C_j (fixed tree) ----
        float4 va = vec4[lane], vb = vec4[lane + 64];
        float s[RPW];
#pragma unroll
        for (int a = 0; a < RPW; ++a)
            s[a] = ((wr[a][0].x * va.x + wr[a][0].y * va.y) +
                    (wr[a][0].z * va.z + wr[a][0].w * va.w)) +
                   ((wr[a][1].x * vb.x + wr[a][1].y * vb.y) +
                    (wr[a][1].z * vb.z + wr[a][1].w * vb.w));
#pragma unroll
        for (int off = 32; off > 0; off >>= 1)
#pragma unroll
            for (int a = 0; a < RPW; ++a) s[a] += __shfl_xor(s[a], off, 64);
#pragma unroll
        for (int a = 0; a < RPW; ++a) Rv[a] = 1.0f / s[a];

        // convergence vote rides the existing syncs (off the critical path)
        if (chk && tid == 0) {
            unsigned f = 0;
#pragma unroll
            for (int w = 0; w < NWAVES; ++w) f |= swflag[w];
            sflag = f;
        }

        // ---- column partials + signed publish (agent scope: eager to IC) ----
        float4 p0 = make_float4(0.f, 0.f, 0.f, 0.f), p1 = p0;
#pragma unroll
        for (int a = 0; a < RPW; ++a) {
            p0.x += wr[a][0].x * Rv[a]; p0.y += wr[a][0].y * Rv[a];
            p0.z += wr[a][0].z * Rv[a]; p0.w += wr[a][0].w * Rv[a];
            p1.x += wr[a][1].x * Rv[a]; p1.y += wr[a][1].y * Rv[a];
            p1.z += wr[a][1].z * Rv[a]; p1.w += wr[a][1].w * Rv[a];
        }
        wp4[lane] = p0;
        wp4[lane + 64] = p1;
        __syncthreads();
        {
            float P = 0.0f;
#pragma unroll
            for (int w = 0; w < NWAVES; ++w) P += wpart[w][tid];   // fixed order
            const float sgnp = ((iter >> 1) & 1) ? -1.0f : 1.0f;
            agent_store_f(&Part[(iter & 1) * (NWORK * N) + slot * N + tid], sgnp * P);
        }
        // Break AFTER publish (uniform across workers); epilogue re-pairs via a
        // final gather so the result ends on a column-normalize like the ref.
        if (chk && sflag == 0) { last = iter; break; }
    }

    // ---- final gather: c = colstep(Rv_last) -> columns sum exactly to 1 ----
    c = gather_c(Part, last, tid);
    __syncthreads();   // all this block's gather loads done before doneflag
    if (tid == 0)
        __hip_atomic_store(&doneflag[slot], TOKEN, __ATOMIC_RELEASE,
                           __HIP_MEMORY_SCOPE_AGENT);
    if (slot == 0) {   // slot 0's rows overlap the Part region — wait for all
        if (tid < NWORK)
            while (__hip_atomic_load(&doneflag[tid], __ATOMIC_ACQUIRE,
                                     __HIP_MEMORY_SCOPE_AGENT) != TOKEN) {}
        __syncthreads();
    }

    // ---- epilogue: out[i][j] = |W0[i][j]| * R_i * C_j (float4 stores) ----
    vec[tid] = c;
    __syncthreads();
    float4 va = vec4[lane], vb = vec4[lane + 64];
    float4* out4 = (float4*)out;
#pragma unroll
    for (int a = 0; a < RPW; ++a) {
        float4 o0, o1;
        o0.x = wr[a][0].x * Rv[a] * va.x; o0.y = wr[a][0].y * Rv[a] * va.y;
        o0.z = wr[a][0].z * Rv[a] * va.z; o0.w = wr[a][0].w * Rv[a] * va.w;
        o1.x = wr[a][1].x * Rv[a] * vb.x; o1.y = wr[a][1].y * Rv[a] * vb.y;
        o1.z = wr[a][1].z * Rv[a] * vb.z; o1.w = wr[a][1].w * Rv[a] * vb.w;
        out4[(r0 + a) * 128 + lane] = o0;
        out4[(r0 + a) * 128 + lane + 64] = o1;
    }
}

extern "C" void kernel_launch(void* const* d_in, const int* in_sizes, int n_in,
                              void* d_out, int out_size, void* d_ws, size_t ws_size,
                              hipStream_t stream) {
    const float* weight = (const float*)d_in[0];
    float* out = (float*)d_out;
    unsigned* ws = (unsigned*)d_ws;

    sinkhorn_persistent<<<NLAUNCH, TPB, 0, stream>>>(weight, out, ws);
}

// Round 12
// 75.851 us; speedup vs baseline: 1.1613x; 1.0864x over previous
//
#include <hip/hip_runtime.h>
#include <math.h>

#define N 512
#define MAX_ITERS 1024
#define NWORK 8                // worker blocks, elected onto ONE XCD
#define NLAUNCH 64             // pigeonhole: some XCD hosts >= 8 of 64 blocks
#define TPB 512                // == N: every thread owns one column
#define NWAVES 8
#define RPW 8                  // rows per wave (NWORK*NWAVES*RPW == N)
#define REL_TOL 1e-5f
#define POISON 0xAAAAAAAAu
#define TOKEN 0x5A5A5A5Au

// ws (unsigned[], poison 0xAAAAAAAA every launch):
//   [0..15] cnt[xcd] tickets, [16] winner CAS, [17..24] doneflag[slot]
// Slice exchange: float Part[2][NWORK][N] = 32 KB in d_out rows 0..15; clobbered
// by slot 0's epilogue only after all doneflags post. Sync is carried by DATA:
// iter i publishes with sign (-1)^((i>>1)&1) (alternates per buffer reuse);
// readers spin until the expected sign appears on all 8 slices. Poison is
// negative; first expected sign of both buffers is +.
// Proven: agent scope (sc1) is the visibility point (sc0/SE hangs — R6);
// 8 sc1 loads batched behind ONE s_waitcnt = one RT per poll round (R7);
// eager agent-scope publish (R10). R11's per-wave-publish/single-sync variant
// HUNG for reasons not explained by the protocol model — do not resurrect.

__device__ __forceinline__ void agent_store_f(float* p, float v) {
    __hip_atomic_store(p, v, __ATOMIC_RELAXED, __HIP_MEMORY_SCOPE_AGENT);
}

__device__ __forceinline__ unsigned read_xcc_id() {
    return __builtin_amdgcn_s_getreg(20 | (3 << 11)) & 15u;   // HW_REG_XCC_ID
}

// 8 agent-scope (sc1) loads in flight, one waitcnt: ~one round trip.
__device__ __forceinline__ void load8_sc1(const float* b0, const float* b1,
                                          const float* b2, const float* b3,
                                          const float* b4, const float* b5,
                                          const float* b6, const float* b7,
                                          float& x0, float& x1, float& x2, float& x3,
                                          float& x4, float& x5, float& x6, float& x7) {
    asm volatile(
        "global_load_dword %0, %[a0], off sc1\n\t"
        "global_load_dword %1, %[a1], off sc1\n\t"
        "global_load_dword %2, %[a2], off sc1\n\t"
        "global_load_dword %3, %[a3], off sc1\n\t"
        "global_load_dword %4, %[a4], off sc1\n\t"
        "global_load_dword %5, %[a5], off sc1\n\t"
        "global_load_dword %6, %[a6], off sc1\n\t"
        "global_load_dword %7, %[a7], off sc1\n\t"
        "s_waitcnt vmcnt(0)"
        : "=&v"(x0), "=&v"(x1), "=&v"(x2), "=&v"(x3),
          "=&v"(x4), "=&v"(x5), "=&v"(x6), "=&v"(x7)
        : [a0]"v"(b0), [a1]"v"(b1), [a2]"v"(b2), [a3]"v"(b3),
          [a4]"v"(b4), [a5]"v"(b5), [a6]"v"(b6), [a7]"v"(b7)
        : "memory");
}

// Spin-gather all NWORK slices of `tag`, fixed-order sum -> C value for col tid.
__device__ __forceinline__ float gather_c(const float* Part, int tag, int tid) {
    const float* base = Part + (tag & 1) * (NWORK * N) + tid;
    const float sgn = ((tag >> 1) & 1) ? -1.0f : 1.0f;
    float v0, v1, v2, v3, v4, v5, v6, v7;
    bool ok;
    do {
        load8_sc1(base, base + N, base + 2 * N, base + 3 * N,
                  base + 4 * N, base + 5 * N, base + 6 * N, base + 7 * N,
                  v0, v1, v2, v3, v4, v5, v6, v7);
        ok = (v0 * sgn > 0.0f) & (v1 * sgn > 0.0f) &
             (v2 * sgn > 0.0f) & (v3 * sgn > 0.0f) &
             (v4 * sgn > 0.0f) & (v5 * sgn > 0.0f) &
             (v6 * sgn > 0.0f) & (v7 * sgn > 0.0f);
    } while (!ok);
    float s = ((v0 + v1) + (v2 + v3)) + ((v4 + v5) + (v6 + v7));
    return sgn / s;
}

__global__ __launch_bounds__(TPB, 2)
void sinkhorn_persistent(const float* __restrict__ W, float* out, unsigned* ws) {
    unsigned* cnt      = ws;        // [16]
    unsigned* winner   = ws + 16;
    unsigned* doneflag = ws + 17;   // [NWORK]
    float* Part = out;              // [2][NWORK][N]

    __shared__ __align__(16) float vec[N];
    __shared__ __align__(16) float wpart[NWAVES][N];
    __shared__ unsigned swflag[NWAVES];
    __shared__ unsigned sflag;
    __shared__ unsigned s_ticket, s_xcd, s_win;

    const int tid  = threadIdx.x;   // == owned column (TPB == N)
    const int wave = tid >> 6;
    const int lane = tid & 63;

    // ---------------- election, phase 1: draw a ticket ----------------
    if (tid == 0) {
        unsigned xcd = read_xcc_id();
        unsigned ticket = __hip_atomic_fetch_add(&cnt[xcd], 1u, __ATOMIC_RELAXED,
                                                 __HIP_MEMORY_SCOPE_AGENT) - POISON;
        s_ticket = ticket; s_xcd = xcd;
        if (ticket == NWORK - 1) {
            unsigned expected = POISON;
            __hip_atomic_compare_exchange_strong(winner, &expected, xcd,
                                                 __ATOMIC_RELAXED, __ATOMIC_RELAXED,
                                                 __HIP_MEMORY_SCOPE_AGENT);
        }
    }
    __syncthreads();
    const unsigned slot = s_ticket;
    if (slot >= NWORK) return;      // can't be a worker on any XCD

    // ---------------- tentative matrix load (overlaps winner wait) ----------
    const int r0 = ((int)slot * NWAVES + wave) * RPW;
    const float4* W4 = (const float4*)W;   // row pitch 128 float4
    float4 wr[RPW][2];
#pragma unroll
    for (int a = 0; a < RPW; ++a)
#pragma unroll
        for (int kk = 0; kk < 2; ++kk) {
            float4 t = W4[(r0 + a) * 128 + lane + 64 * kk];
            wr[a][kk] = make_float4(fabsf(t.x), fabsf(t.y), fabsf(t.z), fabsf(t.w));
        }

    // ---------------- election, phase 2: resolve winner ----------------
    if (tid == 0) {
        unsigned w;
        while ((w = __hip_atomic_load(winner, __ATOMIC_RELAXED,
                                      __HIP_MEMORY_SCOPE_AGENT)) == POISON) {}
        s_win = (s_xcd == w) ? 1u : 0u;
    }
    __syncthreads();
    if (!s_win) return;

    float4* const vec4 = (float4*)vec;
    float4* const wp4  = (float4*)&wpart[wave][0];

    // Identical committed slice values + FIXED summation trees -> bitwise-
    // identical trajectories in all workers -> uniform convergence break.
    float c = 1.0f, h1 = 1.0f, h2 = 1.0f, cchk = 1.0f;
    float Rv[RPW];
#pragma unroll
    for (int a = 0; a < RPW; ++a) Rv[a] = 0.0f;
    int last = MAX_ITERS - 1;
    int extrap_cd = 6;   // first Aitken at iter 6, then every 3 (clean triples)

    for (int iter = 0; iter < MAX_ITERS; ++iter) {
        bool chk = false;
        unsigned anyv = 0;
        if (iter > 0) {
            c = gather_c(Part, iter - 1, tid);
            chk = (iter >= 5);
            if (chk) {
                bool nc = fabsf(c - cchk) > REL_TOL * fabsf(c);
                cchk = c;
                anyv = (unsigned)__any(nc);
            }
            // safeguarded componentwise Aitken delta^2, cadence 3 (start 6):
            // points e+1..e+3 after an extrap at e are a plain orbit -> both
            // diffs geometric -> cadence 3 is the fastest valid schedule.
            if (--extrap_cd == 0) {
                extrap_cd = 3;
                float d1 = c - h1, d0 = h1 - h2;
                float dd = d1 - d0;
                if (fabsf(dd) > 1e-9f * fabsf(c)) {
                    float cx = c - d1 * d1 / dd;
                    if (cx > 0.25f * c && cx < 4.0f * c) c = cx;
                }
            }
            h2 = h1; h1 = c;
        }

        vec[tid] = c;
        if (chk && lane == 0) swflag[wave] = anyv;
        __syncthreads();

        // ---- row step: R_r = 1 / sum_j |W0|[r][j] * C_j (fixed tree) ----
        float4 va = vec4[lane], vb = vec4[lane + 64];
        float s[RPW];
#pragma unroll
        for (int a = 0; a < RPW; ++a)
            s[a] = ((wr[a][0].x * va.x + wr[a][0].y * va.y) +
                    (wr[a][0].z * va.z + wr[a][0].w * va.w)) +
                   ((wr[a][1].x * vb.x + wr[a][1].y * vb.y) +
                    (wr[a][1].z * vb.z + wr[a][1].w * vb.w));
#pragma unroll
        for (int off = 32; off > 0; off >>= 1)
#pragma unroll
            for (int a = 0; a < RPW; ++a) s[a] += __shfl_xor(s[a], off, 64);
#pragma unroll
        for (int a = 0; a < RPW; ++a) Rv[a] = 1.0f / s[a];

        // convergence vote rides the existing syncs (off the critical path)
        if (chk && tid == 0) {
            unsigned f = 0;
#pragma unroll
            for (int w = 0; w < NWAVES; ++w) f |= swflag[w];
            sflag = f;
        }

        // ---- column partials + signed publish (agent scope: eager to IC) ----
        float4 p0 = make_float4(0.f, 0.f, 0.f, 0.f), p1 = p0;
#pragma unroll
        for (int a = 0; a < RPW; ++a) {
            p0.x += wr[a][0].x * Rv[a]; p0.y += wr[a][0].y * Rv[a];
            p0.z += wr[a][0].z * Rv[a]; p0.w += wr[a][0].w * Rv[a];
            p1.x += wr[a][1].x * Rv[a]; p1.y += wr[a][1].y * Rv[a];
            p1.z += wr[a][1].z * Rv[a]; p1.w += wr[a][1].w * Rv[a];
        }
        wp4[lane] = p0;
        wp4[lane + 64] = p1;
        __syncthreads();
        {
            float P = 0.0f;
#pragma unroll
            for (int w = 0; w < NWAVES; ++w) P += wpart[w][tid];   // fixed order
            const float sgnp = ((iter >> 1) & 1) ? -1.0f : 1.0f;
            agent_store_f(&Part[(iter & 1) * (NWORK * N) + slot * N + tid], sgnp * P);
        }
        // Break AFTER publish (uniform across workers); epilogue re-pairs via a
        // final gather so the result ends on a column-normalize like the ref.
        if (chk && sflag == 0) { last = iter; break; }
    }

    // ---- final gather: c = colstep(Rv_last) -> columns sum exactly to 1 ----
    c = gather_c(Part, last, tid);
    __syncthreads();   // all this block's gather loads done before doneflag
    if (tid == 0)
        __hip_atomic_store(&doneflag[slot], TOKEN, __ATOMIC_RELEASE,
                           __HIP_MEMORY_SCOPE_AGENT);
    if (slot == 0) {   // slot 0's rows overlap the Part region — wait for all
        if (tid < NWORK)
            while (__hip_atomic_load(&doneflag[tid], __ATOMIC_ACQUIRE,
                                     __HIP_MEMORY_SCOPE_AGENT) != TOKEN) {}
        __syncthreads();
    }

    // ---- epilogue: out[i][j] = |W0[i][j]| * R_i * C_j (float4 stores) ----
    vec[tid] = c;
    __syncthreads();
    float4 va = vec4[lane], vb = vec4[lane + 64];
    float4* out4 = (float4*)out;
#pragma unroll
    for (int a = 0; a < RPW; ++a) {
        float4 o0, o1;
        o0.x = wr[a][0].x * Rv[a] * va.x; o0.y = wr[a][0].y * Rv[a] * va.y;
        o0.z = wr[a][0].z * Rv[a] * va.z; o0.w = wr[a][0].w * Rv[a] * va.w;
        o1.x = wr[a][1].x * Rv[a] * vb.x; o1.y = wr[a][1].y * Rv[a] * vb.y;
        o1.z = wr[a][1].z * Rv[a] * vb.z; o1.w = wr[a][1].w * Rv[a] * vb.w;
        out4[(r0 + a) * 128 + lane] = o0;
        out4[(r0 + a) * 128 + lane + 64] = o1;
    }
}

extern "C" void kernel_launch(void* const* d_in, const int* in_sizes, int n_in,
                              void* d_out, int out_size, void* d_ws, size_t ws_size,
                              hipStream_t stream) {
    const float* weight = (const float*)d_in[0];
    float* out = (float*)d_out;
    unsigned* ws = (unsigned*)d_ws;

    sinkhorn_persistent<<<NLAUNCH, TPB, 0, stream>>>(weight, out, ws);
}

// Round 13
// 75.085 us; speedup vs baseline: 1.1732x; 1.0102x over previous
//
#include <hip/hip_runtime.h>
#include <math.h>

#define N 512
#define MAX_ITERS 1024
#define NWORK 8                // worker blocks, elected onto ONE XCD
#define NLAUNCH 64             // pigeonhole: some XCD hosts >= 8 of 64 blocks
#define TPB 512                // == N: every thread owns one column
#define NWAVES 8
#define RPW 8                  // rows per wave (NWORK*NWAVES*RPW == N)
#define REL_TOL 1e-5f
#define POISON 0xAAAAAAAAu
#define TOKEN 0x5A5A5A5Au

// ws (unsigned[], poison 0xAAAAAAAA every launch):
//   [0..15] cnt[xcd] tickets, [16] winner CAS, [17..24] doneflag[slot]
// Slice exchange: float Part[2][NWORK][N] = 32 KB in d_out rows 0..15; clobbered
// by slot 0's epilogue only after all doneflags post. Sync is carried by DATA:
// iter i publishes with sign (-1)^((i>>1)&1) (alternates per buffer reuse);
// readers spin until the expected sign appears on all 8 slices. Poison is
// negative; first expected sign of both buffers is +.
// Proven: agent scope (sc1) is the visibility point (sc0/SE hangs — R6);
// 8 sc1 loads batched behind ONE s_waitcnt = one RT per poll round (R7);
// eager agent-scope publish (R10). R11's per-wave-publish/single-sync variant
// HUNG — exchange structure below is byte-identical to R12's proven one.
// R13: 5-point 2-mode extrapolation (kills lambda AND mu; Aitken only killed
// lambda, leaving the mu-envelope to set the stop — R9/R12 evidence), and the
// epilogue's final gather dropped (craw pairing drift < REL_TOL, ~1e-6 abs).

__device__ __forceinline__ void agent_store_f(float* p, float v) {
    __hip_atomic_store(p, v, __ATOMIC_RELAXED, __HIP_MEMORY_SCOPE_AGENT);
}

__device__ __forceinline__ unsigned read_xcc_id() {
    return __builtin_amdgcn_s_getreg(20 | (3 << 11)) & 15u;   // HW_REG_XCC_ID
}

// 8 agent-scope (sc1) loads in flight, one waitcnt: ~one round trip.
__device__ __forceinline__ void load8_sc1(const float* b0, const float* b1,
                                          const float* b2, const float* b3,
                                          const float* b4, const float* b5,
                                          const float* b6, const float* b7,
                                          float& x0, float& x1, float& x2, float& x3,
                                          float& x4, float& x5, float& x6, float& x7) {
    asm volatile(
        "global_load_dword %0, %[a0], off sc1\n\t"
        "global_load_dword %1, %[a1], off sc1\n\t"
        "global_load_dword %2, %[a2], off sc1\n\t"
        "global_load_dword %3, %[a3], off sc1\n\t"
        "global_load_dword %4, %[a4], off sc1\n\t"
        "global_load_dword %5, %[a5], off sc1\n\t"
        "global_load_dword %6, %[a6], off sc1\n\t"
        "global_load_dword %7, %[a7], off sc1\n\t"
        "s_waitcnt vmcnt(0)"
        : "=&v"(x0), "=&v"(x1), "=&v"(x2), "=&v"(x3),
          "=&v"(x4), "=&v"(x5), "=&v"(x6), "=&v"(x7)
        : [a0]"v"(b0), [a1]"v"(b1), [a2]"v"(b2), [a3]"v"(b3),
          [a4]"v"(b4), [a5]"v"(b5), [a6]"v"(b6), [a7]"v"(b7)
        : "memory");
}

// Spin-gather all NWORK slices of `tag`, fixed-order sum -> C value for col tid.
__device__ __forceinline__ float gather_c(const float* Part, int tag, int tid) {
    const float* base = Part + (tag & 1) * (NWORK * N) + tid;
    const float sgn = ((tag >> 1) & 1) ? -1.0f : 1.0f;
    float v0, v1, v2, v3, v4, v5, v6, v7;
    bool ok;
    do {
        load8_sc1(base, base + N, base + 2 * N, base + 3 * N,
                  base + 4 * N, base + 5 * N, base + 6 * N, base + 7 * N,
                  v0, v1, v2, v3, v4, v5, v6, v7);
        ok = (v0 * sgn > 0.0f) & (v1 * sgn > 0.0f) &
             (v2 * sgn > 0.0f) & (v3 * sgn > 0.0f) &
             (v4 * sgn > 0.0f) & (v5 * sgn > 0.0f) &
             (v6 * sgn > 0.0f) & (v7 * sgn > 0.0f);
    } while (!ok);
    float s = ((v0 + v1) + (v2 + v3)) + ((v4 + v5) + (v6 + v7));
    return sgn / s;
}

__global__ __launch_bounds__(TPB, 2)
void sinkhorn_persistent(const float* __restrict__ W, float* out, unsigned* ws) {
    unsigned* cnt      = ws;        // [16]
    unsigned* winner   = ws + 16;
    unsigned* doneflag = ws + 17;   // [NWORK]
    float* Part = out;              // [2][NWORK][N]

    __shared__ __align__(16) float vec[N];
    __shared__ __align__(16) float wpart[NWAVES][N];
    __shared__ unsigned swflag[NWAVES];
    __shared__ unsigned sflag;
    __shared__ unsigned s_ticket, s_xcd, s_win;

    const int tid  = threadIdx.x;   // == owned column (TPB == N)
    const int wave = tid >> 6;
    const int lane = tid & 63;

    // ---------------- election, phase 1: draw a ticket ----------------
    if (tid == 0) {
        unsigned xcd = read_xcc_id();
        unsigned ticket = __hip_atomic_fetch_add(&cnt[xcd], 1u, __ATOMIC_RELAXED,
                                                 __HIP_MEMORY_SCOPE_AGENT) - POISON;
        s_ticket = ticket; s_xcd = xcd;
        if (ticket == NWORK - 1) {
            unsigned expected = POISON;
            __hip_atomic_compare_exchange_strong(winner, &expected, xcd,
                                                 __ATOMIC_RELAXED, __ATOMIC_RELAXED,
                                                 __HIP_MEMORY_SCOPE_AGENT);
        }
    }
    __syncthreads();
    const unsigned slot = s_ticket;
    if (slot >= NWORK) return;      // can't be a worker on any XCD

    // ---------------- tentative matrix load (overlaps winner wait) ----------
    const int r0 = ((int)slot * NWAVES + wave) * RPW;
    const float4* W4 = (const float4*)W;   // row pitch 128 float4
    float4 wr[RPW][2];
#pragma unroll
    for (int a = 0; a < RPW; ++a)
#pragma unroll
        for (int kk = 0; kk < 2; ++kk) {
            float4 t = W4[(r0 + a) * 128 + lane + 64 * kk];
            wr[a][kk] = make_float4(fabsf(t.x), fabsf(t.y), fabsf(t.z), fabsf(t.w));
        }

    // ---------------- election, phase 2: resolve winner ----------------
    if (tid == 0) {
        unsigned w;
        while ((w = __hip_atomic_load(winner, __ATOMIC_RELAXED,
                                      __HIP_MEMORY_SCOPE_AGENT)) == POISON) {}
        s_win = (s_xcd == w) ? 1u : 0u;
    }
    __syncthreads();
    if (!s_win) return;

    float4* const vec4 = (float4*)vec;
    float4* const wp4  = (float4*)&wpart[wave][0];

    // Identical committed slice values + FIXED summation trees -> bitwise-
    // identical trajectories in all workers -> uniform convergence break.
    // History h1..h4 holds RAW colsteps; countdown 5 guarantees each 5-point
    // extrap window (h4,h3,h2,h1,craw) is a clean plain-orbit segment.
    float c = 1.0f, craw = 1.0f, cchk = 1.0f;
    float h1 = 1.0f, h2 = 1.0f, h3 = 1.0f, h4 = 1.0f;
    float Rv[RPW];
#pragma unroll
    for (int a = 0; a < RPW; ++a) Rv[a] = 0.0f;
    int extrap_cd = 6;   // first extrap at iter 6 (window craw_2..craw_6)

    for (int iter = 0; iter < MAX_ITERS; ++iter) {
        bool chk = false;
        unsigned anyv = 0;
        if (iter > 0) {
            craw = gather_c(Part, iter - 1, tid);
            c = craw;
            chk = (iter >= 5);
            if (chk) {                       // raw-sequence convergence vote
                bool nc = fabsf(c - cchk) > REL_TOL * fabsf(c);
                cchk = c;
                anyv = (unsigned)__any(nc);
            }
            // ---- 5-point 2-mode extrapolation (MPE-2), cadence 5 ----
            // x0..x4 = h4,h3,h2,h1,c ; d_n = x_{n+1}-x_n ;
            // d2=p d1+q d0, d3=p d2+q d1 ; L=(x4-p x3-q x2)/(1-p-q).
            if (--extrap_cd == 0) {
                extrap_cd = 5;
                float d0 = h3 - h4, d1 = h2 - h3, d2 = h1 - h2, d3 = c - h1;
                float det = d1 * d1 - d0 * d2;
                float L = c;
                bool okm = fabsf(det) > 1e-12f + 1e-6f * fabsf(d1 * d1);
                if (okm) {
                    float p = (d2 * d1 - d0 * d3) / det;
                    float q = (d1 * d3 - d2 * d2) / det;
                    float denL = 1.0f - p - q;
                    if (fabsf(denL) > 1e-4f) L = (c - p * h1 - q * h2) / denL;
                    else okm = false;
                }
                if (!okm) {                  // fallback: Aitken on window tail
                    float dd = d3 - d2;
                    if (fabsf(dd) > 1e-9f * fabsf(c)) L = c - d3 * d3 / dd;
                }
                if (L > 0.25f * c && L < 4.0f * c) c = L;   // safeguard
            }
            h4 = h3; h3 = h2; h2 = h1; h1 = craw;   // RAW history
        }

        vec[tid] = c;
        if (chk && lane == 0) swflag[wave] = anyv;
        __syncthreads();

        // ---- row step: R_r = 1 / sum_j |W0|[r][j] * C_j (fixed tree) ----
        float4 va = vec4[lane], vb = vec4[lane + 64];
        float s[RPW];
#pragma unroll
        for (int a = 0; a < RPW; ++a)
            s[a] = ((wr[a][0].x * va.x + wr[a][0].y * va.y) +
                    (wr[a][0].z * va.z + wr[a][0].w * va.w)) +
                   ((wr[a][1].x * vb.x + wr[a][1].y * vb.y) +
                    (wr[a][1].z * vb.z + wr[a][1].w * vb.w));
#pragma unroll
        for (int off = 32; off > 0; off >>= 1)
#pragma unroll
            for (int a = 0; a < RPW; ++a) s[a] += __shfl_xor(s[a], off, 64);
#pragma unroll
        for (int a = 0; a < RPW; ++a) Rv[a] = 1.0f / s[a];

        // convergence vote rides the existing syncs (off the critical path)
        if (chk && tid == 0) {
            unsigned f = 0;
#pragma unroll
            for (int w = 0; w < NWAVES; ++w) f |= swflag[w];
            sflag = f;
        }

        // ---- column partials + signed publish (agent scope: eager to IC) ----
        float4 p0 = make_float4(0.f, 0.f, 0.f, 0.f), p1 = p0;
#pragma unroll
        for (int a = 0; a < RPW; ++a) {
            p0.x += wr[a][0].x * Rv[a]; p0.y += wr[a][0].y * Rv[a];
            p0.z += wr[a][0].z * Rv[a]; p0.w += wr[a][0].w * Rv[a];
            p1.x += wr[a][1].x * Rv[a]; p1.y += wr[a][1].y * Rv[a];
            p1.z += wr[a][1].z * Rv[a]; p1.w += wr[a][1].w * Rv[a];
        }
        wp4[lane] = p0;
        wp4[lane + 64] = p1;
        __syncthreads();
        {
            float P = 0.0f;
#pragma unroll
            for (int w = 0; w < NWAVES; ++w) P += wpart[w][tid];   // fixed order
            const float sgnp = ((iter >> 1) & 1) ? -1.0f : 1.0f;
            agent_store_f(&Part[(iter & 1) * (NWORK * N) + slot * N + tid], sgnp * P);
        }
        // Break AFTER publish (uniform across workers). Nobody reads the tag
        // published at the break iteration, so no final gather is needed:
        // epilogue pairs (Rv_last, craw=colstep(Rv_{last-1})) — drift < REL_TOL
        // relative => ~1e-6 absolute on outputs, well inside the margin.
        if (chk && sflag == 0) break;
    }

    // ---- epilogue sync: all this block's Part reads are done (they precede
    // the break); publish craw to vec, post doneflag, slot 0 waits before
    // clobbering the Part region (its rows 0..15). ----
    vec[tid] = craw;
    __syncthreads();
    if (tid == 0)
        __hip_atomic_store(&doneflag[slot], TOKEN, __ATOMIC_RELEASE,
                           __HIP_MEMORY_SCOPE_AGENT);
    if (slot == 0) {
        if (tid < NWORK)
            while (__hip_atomic_load(&doneflag[tid], __ATOMIC_ACQUIRE,
                                     __HIP_MEMORY_SCOPE_AGENT) != TOKEN) {}
        __syncthreads();
    }

    // ---- out[i][j] = |W0[i][j]| * R_i * C_j (float4 stores) ----
    float4 va = vec4[lane], vb = vec4[lane + 64];
    float4* out4 = (float4*)out;
#pragma unroll
    for (int a = 0; a < RPW; ++a) {
        float4 o0, o1;
        o0.x = wr[a][0].x * Rv[a] * va.x; o0.y = wr[a][0].y * Rv[a] * va.y;
        o0.z = wr[a][0].z * Rv[a] * va.z; o0.w = wr[a][0].w * Rv[a] * va.w;
        o1.x = wr[a][1].x * Rv[a] * vb.x; o1.y = wr[a][1].y * Rv[a] * vb.y;
        o1.z = wr[a][1].z * Rv[a] * vb.z; o1.w = wr[a][1].w * Rv[a] * vb.w;
        out4[(r0 + a) * 128 + lane] = o0;
        out4[(r0 + a) * 128 + lane + 64] = o1;
    }
}

extern "C" void kernel_launch(void* const* d_in, const int* in_sizes, int n_in,
                              void* d_out, int out_size, void* d_ws, size_t ws_size,
                              hipStream_t stream) {
    const float* weight = (const float*)d_in[0];
    float* out = (float*)d_out;
    unsigned* ws = (unsigned*)d_ws;

    sinkhorn_persistent<<<NLAUNCH, TPB, 0, stream>>>(weight, out, ws);
}